// Round 13
// baseline (512.249 us; speedup 1.0000x reference)
//
#include <hip/hip_runtime.h>
#include <hip/hip_bf16.h>

// FrameTransformer: B=16, C=8, BINS=1024, W=256, FF=2048, NB=4
// tokens = B*W = 4096, feature width 1024, FF width 4096, head dim 256.
#define EPSF 1e-5f

typedef unsigned short u16;
typedef unsigned int   u32;
typedef __attribute__((ext_vector_type(8))) short bf16x8;
typedef __attribute__((ext_vector_type(4))) float f32x4;

// 3-bit XOR swizzle for 64-elem (128 B) LDS rows.
#define SWZ(row) (((row) & 7) << 3)

__device__ __forceinline__ u16 f2bf(float f) {
    u32 u = __builtin_bit_cast(u32, f);
    u32 r = u + 0x7fffu + ((u >> 16) & 1u);
    return (u16)(r >> 16);
}
__device__ __forceinline__ float bf2f(u16 h) {
    return __builtin_bit_cast(float, (u32)h << 16);
}
__device__ __forceinline__ float4 bf4f(ushort4 v) {
    return make_float4(bf2f(v.x), bf2f(v.y), bf2f(v.z), bf2f(v.w));
}
__device__ __forceinline__ ushort4 f4bf(float a, float b, float c, float d) {
    ushort4 o; o.x = f2bf(a); o.y = f2bf(b); o.z = f2bf(c); o.w = f2bf(d); return o;
}
__device__ __forceinline__ void gld16(void* lds, const void* gsrc) {
    __builtin_amdgcn_global_load_lds(
        (const __attribute__((address_space(1))) u32*)gsrc,
        (__attribute__((address_space(3))) u32*)lds, 16, 0, 0);
}

__device__ __forceinline__ float wred_sum(float v) {
#pragma unroll
    for (int off = 32; off; off >>= 1) v += __shfl_xor(v, off, 64);
    return v;
}
__device__ __forceinline__ void block_red2(float& s1, float& s2, int tid) {
    __shared__ float red[8];
    s1 = wred_sum(s1); s2 = wred_sum(s2);
    const int lane = tid & 63, wid = tid >> 6;
    if (!lane) { red[wid] = s1; red[4 + wid] = s2; }
    __syncthreads();
    s1 = red[0] + red[1] + red[2] + red[3];
    s2 = red[4] + red[5] + red[6] + red[7];
}

// ---------------- merged setup: all weight conversions in one launch ----------------
// kw (seg 6) and kb (bias middle third) pre-scaled by 1/32 (skew fold).
struct SetupArgs {
    const float* ws[9]; u16* wd[9]; int wn[9];
    const float* c1r; u16* c1rd;
    const float* er;  u16* erd;
    const float* dw;  float* dwd;
    const float* qb;  const float* kb; const float* vb; float* bcat;
    u16* zp;
    int off[15];
};
__global__ __launch_bounds__(256)
void setup_k(SetupArgs a)
{
    const int b = blockIdx.x;
    int seg = 0;
    while (seg < 13 && b >= a.off[seg + 1]) ++seg;
    const int i = (b - a.off[seg]) * 256 + threadIdx.x;
    if (seg < 9) {
        if (i < a.wn[seg]) {
            const float4 v = ((const float4*)a.ws[seg])[i];
            const float s = (seg == 6) ? 0.03125f : 1.f;
            ((ushort4*)a.wd[seg])[i] = f4bf(v.x * s, v.y * s, v.z * s, v.w * s);
        }
    } else if (seg == 9) {
        if (i < 3145728) {
            const int q = i / 3072, rem = i - q * 3072;
            const int ks = rem >> 10, ci = rem & 1023;
            a.c1rd[i] = f2bf(a.c1r[((long)q * 1024 + ci) * 3 + ks]);
        }
    } else if (seg == 10) {
        if (i < 65536) { const int c = i >> 8, d = i & 255; a.erd[i] = f2bf(a.er[d * 256 + c]); }
    } else if (seg == 11) {
        if (i < 36864) { const int k = i >> 12, c = i & 4095; a.dwd[i] = a.dw[c * 9 + k]; }
    } else if (seg == 12) {
        if (i < 3072) {
            const float* s = (i < 1024) ? a.qb : ((i < 2048) ? a.kb : a.vb);
            float v = s[i & 1023];
            if (i >= 1024 && i < 2048) v *= 0.03125f;
            a.bcat[i] = v;
        }
    } else {
        if (i < 8192) a.zp[i] = 0;
    }
}

// ---------------- stage 1: bottleneck 1x1 conv + BN + ReLU + transpose (bf16 out) ----------------
__global__ __launch_bounds__(256)
void bottleneck_k(const float* __restrict__ x, const float* __restrict__ bw,
                  const float* __restrict__ bn_g, const float* __restrict__ bn_b,
                  const float* __restrict__ bn_m, const float* __restrict__ bn_v,
                  u16* __restrict__ xsb)
{
    __shared__ float tile[32][33];
    const int b = blockIdx.z, h0 = blockIdx.y * 32, w0 = blockIdx.x * 32;
    const int tid = threadIdx.x;
    const int tw = tid & 7, th = tid >> 3;
    float wreg[8];
#pragma unroll
    for (int ch = 0; ch < 8; ++ch) wreg[ch] = bw[ch];
    const float sc = bn_g[0] * rsqrtf(bn_v[0] + EPSF);
    const float sh = bn_b[0] - bn_m[0] * sc;
    float4 acc = make_float4(0.f, 0.f, 0.f, 0.f);
#pragma unroll
    for (int ch = 0; ch < 8; ++ch) {
        const float4 v = *(const float4*)&x[(((long)b * 8 + ch) * 1024 + h0 + th) * 256 + w0 + tw * 4];
        acc.x += v.x * wreg[ch]; acc.y += v.y * wreg[ch];
        acc.z += v.z * wreg[ch]; acc.w += v.w * wreg[ch];
    }
    tile[th][tw * 4 + 0] = fmaxf(acc.x * sc + sh, 0.f);
    tile[th][tw * 4 + 1] = fmaxf(acc.y * sc + sh, 0.f);
    tile[th][tw * 4 + 2] = fmaxf(acc.z * sc + sh, 0.f);
    tile[th][tw * 4 + 3] = fmaxf(acc.w * sc + sh, 0.f);
    __syncthreads();
    const int c = tid & 31, r = tid >> 5;
#pragma unroll
    for (int it = 0; it < 4; ++it) {
        const int wl = r + it * 8;
        xsb[((long)b * 256 + w0 + wl) * 1024 + h0 + c] = f2bf(tile[c][wl]);
    }
}

// ============ 8-phase 256x256 bf16 MFMA GEMM (T2+T3+T4+T5) ============
// VOUT: for N-tiles with n0>=2048 (V region of fused QKV), write transposed per head.
template<int ACT, int OUTBF, int BIAS, int SPLITK, int VOUT>
__global__ __launch_bounds__(512, 2)
void gemm8_k(const u16* __restrict__ A, const u16* __restrict__ B,
             const float* __restrict__ bias, void* __restrict__ Cout,
             int N, int K /*per slice*/, int lda, int ldb, long partStride,
             u16* __restrict__ Vtp)
{
    extern __shared__ u16 lds[];
    const int m0 = blockIdx.y * 256, n0 = blockIdx.x * 256;
    const int koff = (SPLITK > 1) ? blockIdx.z * K : 0;
    const int nt = K >> 6;
    const int tid = threadIdx.x;
    const int lane = tid & 63, wid = tid >> 6;
    const int wr = ((wid >> 2) & 1) * 128;
    const int wc = (wid & 3) * 64;
    const int l15 = lane & 15, l4 = lane >> 4;

    const u16* Ag = A + (long)m0 * lda + koff;
    const u16* Bg = B + (long)n0 * ldb + koff;

    auto stage = [&](const u16* g, int ld, int ldsbase, int kcol, int h) {
#pragma unroll
        for (int is = 0; is < 2; ++is) {
            const int r = h * 128 + is * 64 + (tid >> 3);
            const int sc = ((tid & 7) * 8) ^ SWZ(r);
            gld16(&lds[ldsbase + h * 8192 + is * 4096 + tid * 8],
                  g + (long)r * ld + kcol + sc);
        }
    };
    auto frag = [&](int base, int row, int col) -> bf16x8 {
        return *(const bf16x8*)&lds[base + row * 64 + (col ^ SWZ(row))];
    };

    f32x4 acc[8][4] = {};

    stage(Ag, lda, 0, 0, 0);
    stage(Ag, lda, 0, 0, 1);
    stage(Bg, ldb, 32768, 0, 0);
    stage(Bg, ldb, 32768, 0, 1);
    if (nt > 1) {
        stage(Bg, ldb, 49152, 64, 0);
        stage(Bg, ldb, 49152, 64, 1);
        stage(Ag, lda, 16384, 64, 0);
        asm volatile("s_waitcnt vmcnt(6)" ::: "memory");
    } else {
        asm volatile("s_waitcnt vmcnt(0)" ::: "memory");
    }
    __builtin_amdgcn_s_barrier();

    for (int kt = 0; kt < nt; ++kt) {
        const int cs = kt & 1;
        const int ab = cs * 16384;
        const int bb = 32768 + cs * 16384;
        const int abn = (cs ^ 1) * 16384;
        const int kc1 = (kt + 1) * 64, kc2 = (kt + 2) * 64;
        bf16x8 alo[4][2], ahi[4][2], b01[2][2], b23[2][2];

#pragma unroll
        for (int i = 0; i < 4; ++i)
#pragma unroll
            for (int kk = 0; kk < 2; ++kk)
                alo[i][kk] = frag(ab, wr + i * 16 + l15, kk * 32 + l4 * 8);
#pragma unroll
        for (int j = 0; j < 2; ++j)
#pragma unroll
            for (int kk = 0; kk < 2; ++kk)
                b01[j][kk] = frag(bb, wc + j * 16 + l15, kk * 32 + l4 * 8);
        if (kt + 1 < nt) stage(Ag, lda, abn, kc1, 1);
        __builtin_amdgcn_s_barrier();
        asm volatile("s_waitcnt lgkmcnt(0)" ::: "memory");
        __builtin_amdgcn_s_setprio(1);
#pragma unroll
        for (int i = 0; i < 4; ++i)
#pragma unroll
            for (int j = 0; j < 2; ++j)
#pragma unroll
                for (int kk = 0; kk < 2; ++kk)
                    acc[i][j] = __builtin_amdgcn_mfma_f32_16x16x32_bf16(alo[i][kk], b01[j][kk], acc[i][j], 0, 0, 0);
        __builtin_amdgcn_s_setprio(0);
        __builtin_amdgcn_s_barrier();

#pragma unroll
        for (int j = 0; j < 2; ++j)
#pragma unroll
            for (int kk = 0; kk < 2; ++kk)
                b23[j][kk] = frag(bb, wc + (j + 2) * 16 + l15, kk * 32 + l4 * 8);
        if (kt + 2 < nt) stage(Bg, ldb, bb, kc2, 0);
        __builtin_amdgcn_s_barrier();
        asm volatile("s_waitcnt lgkmcnt(0)" ::: "memory");
        __builtin_amdgcn_s_setprio(1);
#pragma unroll
        for (int i = 0; i < 4; ++i)
#pragma unroll
            for (int j = 0; j < 2; ++j)
#pragma unroll
                for (int kk = 0; kk < 2; ++kk)
                    acc[i][j + 2] = __builtin_amdgcn_mfma_f32_16x16x32_bf16(alo[i][kk], b23[j][kk], acc[i][j + 2], 0, 0, 0);
        __builtin_amdgcn_s_setprio(0);
        __builtin_amdgcn_s_barrier();

#pragma unroll
        for (int i = 0; i < 4; ++i)
#pragma unroll
            for (int kk = 0; kk < 2; ++kk)
                ahi[i][kk] = frag(ab, wr + (i + 4) * 16 + l15, kk * 32 + l4 * 8);
        if (kt + 2 < nt) stage(Bg, ldb, bb, kc2, 1);
        __builtin_amdgcn_s_barrier();
        asm volatile("s_waitcnt lgkmcnt(0)" ::: "memory");
        __builtin_amdgcn_s_setprio(1);
#pragma unroll
        for (int i = 0; i < 4; ++i)
#pragma unroll
            for (int j = 0; j < 2; ++j)
#pragma unroll
                for (int kk = 0; kk < 2; ++kk)
                    acc[i + 4][j + 2] = __builtin_amdgcn_mfma_f32_16x16x32_bf16(ahi[i][kk], b23[j][kk], acc[i + 4][j + 2], 0, 0, 0);
        __builtin_amdgcn_s_setprio(0);
        __builtin_amdgcn_s_barrier();

        if (kt + 2 < nt) stage(Ag, lda, ab, kc2, 0);
        __builtin_amdgcn_s_barrier();
        __builtin_amdgcn_s_setprio(1);
#pragma unroll
        for (int i = 0; i < 4; ++i)
#pragma unroll
            for (int j = 0; j < 2; ++j)
#pragma unroll
                for (int kk = 0; kk < 2; ++kk)
                    acc[i + 4][j] = __builtin_amdgcn_mfma_f32_16x16x32_bf16(ahi[i][kk], b01[j][kk], acc[i + 4][j], 0, 0, 0);
        __builtin_amdgcn_s_setprio(0);
        if (kt + 2 < nt) {
            asm volatile("s_waitcnt vmcnt(6)" ::: "memory");
        } else {
            asm volatile("s_waitcnt vmcnt(0)" ::: "memory");
        }
        __builtin_amdgcn_s_barrier();
    }

    if (VOUT && n0 >= 2048) {
        const int zb4 = (m0 >> 8) * 4;
#pragma unroll
        for (int i = 0; i < 8; ++i)
#pragma unroll
            for (int j = 0; j < 4; ++j) {
                const int n = n0 + wc + j * 16 + l15;
                const int d = n - 2048, zn = d >> 8, dl = d & 255;
                const float bv = BIAS ? bias[n] : 0.f;
                const int w = wr + i * 16 + l4 * 4;
                ushort4 st = f4bf(acc[i][j][0] + bv, acc[i][j][1] + bv,
                                  acc[i][j][2] + bv, acc[i][j][3] + bv);
                *(ushort4*)&Vtp[((long)(zb4 + zn) * 256 + dl) * 256 + w] = st;
            }
    } else if (SPLITK > 1) {
        u16* Cp = (u16*)Cout + (long)blockIdx.z * partStride;
#pragma unroll
        for (int i = 0; i < 8; ++i)
#pragma unroll
            for (int j = 0; j < 4; ++j) {
                const int n = n0 + wc + j * 16 + l15;
#pragma unroll
                for (int q = 0; q < 4; ++q) {
                    const int m = m0 + wr + i * 16 + l4 * 4 + q;
                    Cp[(long)m * N + n] = f2bf(acc[i][j][q]);
                }
            }
    } else {
        float* Cf = (float*)Cout;
        u16*   Cb = (u16*)Cout;
#pragma unroll
        for (int i = 0; i < 8; ++i)
#pragma unroll
            for (int j = 0; j < 4; ++j) {
                const int n = n0 + wc + j * 16 + l15;
                const float bv = BIAS ? bias[n] : 0.f;
#pragma unroll
                for (int q = 0; q < 4; ++q) {
                    const int m = m0 + wr + i * 16 + l4 * 4 + q;
                    float v = acc[i][j][q] + bv;
                    if (ACT) v = fmaxf(v, 0.f);
                    if (OUTBF) Cb[(long)m * N + n] = f2bf(v);
                    else       Cf[(long)m * N + n] = v;
                }
            }
    }
}

// ============ merged c1L + conv1R launch (8-phase body) ============
// bx<16: c1L N-tile (K=1024, nt=16, relu -> Hout N=4096).
// bx>=16: conv with full K'=3072 (nt=48), taps folded into K; relu'd bf16
// direct to C3s (no partials). shift = (kcol>>10)-1, ci = kcol&1023.
__global__ __launch_bounds__(512, 2)
void ffconv8_k(const u16* __restrict__ Xb, const u16* __restrict__ Wl,
               const u16* __restrict__ Wr, const u16* __restrict__ zp,
               u16* __restrict__ Hout, u16* __restrict__ C3s)
{
    extern __shared__ u16 lds[];
    const int bx = blockIdx.x;
    const int m0 = blockIdx.y * 256;
    const bool conv = bx >= 16;
    const int n0 = conv ? ((bx - 16) * 256) : (bx * 256);
    const u16* Bbase = conv ? (Wr + (long)n0 * 3072) : (Wl + (long)n0 * 1024);
    const int ldb = conv ? 3072 : 1024;
    const int nt = conv ? 48 : 16;
    const int tid = threadIdx.x;
    const int lane = tid & 63, wid = tid >> 6;
    const int wr = ((wid >> 2) & 1) * 128;
    const int wc = (wid & 3) * 64;
    const int l15 = lane & 15, l4 = lane >> 4;

    auto stageA = [&](int ldsbase, int kcol, int h) {
        const int shift = conv ? ((kcol >> 10) - 1) : 0;
        const int ci = conv ? (kcol & 1023) : kcol;
#pragma unroll
        for (int is = 0; is < 2; ++is) {
            const int r = h * 128 + is * 64 + (tid >> 3);
            const int sc = ((tid & 7) * 8) ^ SWZ(r);
            const int t = m0 + r;
            const int wp = (t & 255) + shift;
            const u16* src = ((unsigned)wp < 256u)
                ? Xb + (long)(t + shift) * 1024 + ci + sc
                : zp;
            gld16(&lds[ldsbase + h * 8192 + is * 4096 + tid * 8], src);
        }
    };
    auto stageB = [&](int ldsbase, int kcol, int h) {
#pragma unroll
        for (int is = 0; is < 2; ++is) {
            const int r = h * 128 + is * 64 + (tid >> 3);
            const int sc = ((tid & 7) * 8) ^ SWZ(r);
            gld16(&lds[ldsbase + h * 8192 + is * 4096 + tid * 8],
                  Bbase + (long)r * ldb + kcol + sc);
        }
    };
    auto frag = [&](int base, int row, int col) -> bf16x8 {
        return *(const bf16x8*)&lds[base + row * 64 + (col ^ SWZ(row))];
    };

    f32x4 acc[8][4] = {};

    stageA(0, 0, 0);
    stageA(0, 0, 1);
    stageB(32768, 0, 0);
    stageB(32768, 0, 1);
    stageB(49152, 64, 0);
    stageB(49152, 64, 1);
    stageA(16384, 64, 0);
    asm volatile("s_waitcnt vmcnt(6)" ::: "memory");
    __builtin_amdgcn_s_barrier();

    for (int kt = 0; kt < nt; ++kt) {
        const int cs = kt & 1;
        const int ab = cs * 16384;
        const int bb = 32768 + cs * 16384;
        const int abn = (cs ^ 1) * 16384;
        const int kc1 = (kt + 1) * 64, kc2 = (kt + 2) * 64;
        bf16x8 alo[4][2], ahi[4][2], b01[2][2], b23[2][2];

#pragma unroll
        for (int i = 0; i < 4; ++i)
#pragma unroll
            for (int kk = 0; kk < 2; ++kk)
                alo[i][kk] = frag(ab, wr + i * 16 + l15, kk * 32 + l4 * 8);
#pragma unroll
        for (int j = 0; j < 2; ++j)
#pragma unroll
            for (int kk = 0; kk < 2; ++kk)
                b01[j][kk] = frag(bb, wc + j * 16 + l15, kk * 32 + l4 * 8);
        if (kt + 1 < nt) stageA(abn, kc1, 1);
        __builtin_amdgcn_s_barrier();
        asm volatile("s_waitcnt lgkmcnt(0)" ::: "memory");
        __builtin_amdgcn_s_setprio(1);
#pragma unroll
        for (int i = 0; i < 4; ++i)
#pragma unroll
            for (int j = 0; j < 2; ++j)
#pragma unroll
                for (int kk = 0; kk < 2; ++kk)
                    acc[i][j] = __builtin_amdgcn_mfma_f32_16x16x32_bf16(alo[i][kk], b01[j][kk], acc[i][j], 0, 0, 0);
        __builtin_amdgcn_s_setprio(0);
        __builtin_amdgcn_s_barrier();

#pragma unroll
        for (int j = 0; j < 2; ++j)
#pragma unroll
            for (int kk = 0; kk < 2; ++kk)
                b23[j][kk] = frag(bb, wc + (j + 2) * 16 + l15, kk * 32 + l4 * 8);
        if (kt + 2 < nt) stageB(bb, kc2, 0);
        __builtin_amdgcn_s_barrier();
        asm volatile("s_waitcnt lgkmcnt(0)" ::: "memory");
        __builtin_amdgcn_s_setprio(1);
#pragma unroll
        for (int i = 0; i < 4; ++i)
#pragma unroll
            for (int j = 0; j < 2; ++j)
#pragma unroll
                for (int kk = 0; kk < 2; ++kk)
                    acc[i][j + 2] = __builtin_amdgcn_mfma_f32_16x16x32_bf16(alo[i][kk], b23[j][kk], acc[i][j + 2], 0, 0, 0);
        __builtin_amdgcn_s_setprio(0);
        __builtin_amdgcn_s_barrier();

#pragma unroll
        for (int i = 0; i < 4; ++i)
#pragma unroll
            for (int kk = 0; kk < 2; ++kk)
                ahi[i][kk] = frag(ab, wr + (i + 4) * 16 + l15, kk * 32 + l4 * 8);
        if (kt + 2 < nt) stageB(bb, kc2, 1);
        __builtin_amdgcn_s_barrier();
        asm volatile("s_waitcnt lgkmcnt(0)" ::: "memory");
        __builtin_amdgcn_s_setprio(1);
#pragma unroll
        for (int i = 0; i < 4; ++i)
#pragma unroll
            for (int j = 0; j < 2; ++j)
#pragma unroll
                for (int kk = 0; kk < 2; ++kk)
                    acc[i + 4][j + 2] = __builtin_amdgcn_mfma_f32_16x16x32_bf16(ahi[i][kk], b23[j][kk], acc[i + 4][j + 2], 0, 0, 0);
        __builtin_amdgcn_s_setprio(0);
        __builtin_amdgcn_s_barrier();

        if (kt + 2 < nt) stageA(ab, kc2, 0);
        __builtin_amdgcn_s_barrier();
        __builtin_amdgcn_s_setprio(1);
#pragma unroll
        for (int i = 0; i < 4; ++i)
#pragma unroll
            for (int j = 0; j < 2; ++j)
#pragma unroll
                for (int kk = 0; kk < 2; ++kk)
                    acc[i + 4][j] = __builtin_amdgcn_mfma_f32_16x16x32_bf16(ahi[i][kk], b01[j][kk], acc[i + 4][j], 0, 0, 0);
        __builtin_amdgcn_s_setprio(0);
        if (kt + 2 < nt) {
            asm volatile("s_waitcnt vmcnt(6)" ::: "memory");
        } else {
            asm volatile("s_waitcnt vmcnt(0)" ::: "memory");
        }
        __builtin_amdgcn_s_barrier();
    }

    if (conv) {
#pragma unroll
        for (int i = 0; i < 8; ++i)
#pragma unroll
            for (int j = 0; j < 4; ++j) {
                const int n = n0 + wc + j * 16 + l15;
#pragma unroll
                for (int q = 0; q < 4; ++q) {
                    const int m = m0 + wr + i * 16 + l4 * 4 + q;
                    C3s[(long)m * 1024 + n] = f2bf(fmaxf(acc[i][j][q], 0.f));
                }
            }
    } else {
#pragma unroll
        for (int i = 0; i < 8; ++i)
#pragma unroll
            for (int j = 0; j < 4; ++j) {
                const int n = n0 + wc + j * 16 + l15;
#pragma unroll
                for (int q = 0; q < 4; ++q) {
                    const int m = m0 + wr + i * 16 + l4 * 4 + q;
                    Hout[(long)m * 4096 + n] = f2bf(fmaxf(acc[i][j][q], 0.f));
                }
            }
    }
}

// ============ fused attention: one K=512 concat score GEMM -> softmax -> PV ============
__global__ __launch_bounds__(256, 2)
void attn_fused_k(const u16* __restrict__ QKVb, const u16* __restrict__ erT,
                  const u16* __restrict__ Vt, const float* __restrict__ dwp,
                  u16* __restrict__ Oc)
{
    __shared__ __align__(16) u16 As[4096];
    __shared__ __align__(16) u16 Bs[16384];
    __shared__ __align__(16) u16 Pl[16384];
    __shared__ float redM[4][64];
    __shared__ float redS[4][64];
    const int z = blockIdx.y, zb = z >> 2, zn = z & 3;
    const int m0 = blockIdx.x * 64;
    const int tid = threadIdx.x;
    const int lane = tid & 63, wid = tid >> 6;
    const int l15 = lane & 15, l4 = lane >> 4;

    const u16* Qg = QKVb + (long)(zb * 256) * 3072 + zn * 256;
    const u16* Kg = Qg + 1024;   // holds K/32

    auto stageA64 = [&](const u16* g, long ld) {
#pragma unroll
        for (int p = 0; p < 2; ++p) {
            const int e = p * 2048 + tid * 8;
            const int r = e >> 6, c = e & 63;
            const int sc = c ^ SWZ(r);
            gld16(&As[e], g + (long)r * ld + sc);
        }
    };
    auto stageB256 = [&](const u16* g, long ld) {
#pragma unroll
        for (int p = 0; p < 8; ++p) {
            const int e = p * 2048 + tid * 8;
            const int r = e >> 6, c = e & 63;
            const int sc = c ^ SWZ(r);
            gld16(&Bs[e], g + (long)r * ld + sc);
        }
    };
    auto fragA = [&](int i, int kk) -> bf16x8 {
        const int row = i * 16 + l15, col = kk * 32 + l4 * 8;
        return *(const bf16x8*)&As[row * 64 + (col ^ SWZ(row))];
    };
    auto fragB = [&](int j, int kk) -> bf16x8 {
        const int row = wid * 64 + j * 16 + l15, col = kk * 32 + l4 * 8;
        return *(const bf16x8*)&Bs[row * 64 + (col ^ SWZ(row))];
    };
    auto fragP = [&](int kc, int i, int kk) -> bf16x8 {
        const int row = i * 16 + l15, col = kk * 32 + l4 * 8;
        return *(const bf16x8*)&Pl[kc * 4096 + row * 64 + (col ^ SWZ(row))];
    };

    f32x4 acc1[4][4] = {};

    for (int kc = 0; kc < 8; ++kc) {
        __syncthreads();
        if (kc < 4) {
            stageA64(Qg + (long)m0 * 3072 + kc * 64, 3072);
            stageB256(Kg + kc * 64, 3072);
        } else {
            stageA64(erT + (long)m0 * 256 + (kc - 4) * 64, 256);
            stageB256(Qg + (kc - 4) * 64, 3072);
        }
        __syncthreads();
#pragma unroll
        for (int i = 0; i < 4; ++i) {
            const bf16x8 a0 = fragA(i, 0), a1 = fragA(i, 1);
#pragma unroll
            for (int j = 0; j < 4; ++j) {
                acc1[i][j] = __builtin_amdgcn_mfma_f32_16x16x32_bf16(a0, fragB(j, 0), acc1[i][j], 0, 0, 0);
                acc1[i][j] = __builtin_amdgcn_mfma_f32_16x16x32_bf16(a1, fragB(j, 1), acc1[i][j], 0, 0, 0);
            }
        }
    }

#pragma unroll
    for (int i = 0; i < 4; ++i)
#pragma unroll
        for (int q = 0; q < 4; ++q) {
            const int mg = m0 + i * 16 + l4 * 4 + q;
            const float dw = dwp[zn * 256 + mg];
#pragma unroll
            for (int j = 0; j < 4; ++j) {
                const int ng = wid * 64 + j * 16 + l15;
                acc1[i][j][q] += fabsf((float)(mg - ng)) * 0.5f * dw;
            }
        }

    float rmax[4][4], rsum[4][4];
#pragma unroll
    for (int i = 0; i < 4; ++i)
#pragma unroll
        for (int q = 0; q < 4; ++q) {
            float mv = fmaxf(fmaxf(acc1[i][0][q], acc1[i][1][q]),
                             fmaxf(acc1[i][2][q], acc1[i][3][q]));
#pragma unroll
            for (int off = 1; off <= 8; off <<= 1) mv = fmaxf(mv, __shfl_xor(mv, off, 64));
            rmax[i][q] = mv;
        }
    if (l15 == 0) {
#pragma unroll
        for (int i = 0; i < 4; ++i)
#pragma unroll
            for (int q = 0; q < 4; ++q)
                redM[wid][i * 16 + l4 * 4 + q] = rmax[i][q];
    }
    __syncthreads();
#pragma unroll
    for (int i = 0; i < 4; ++i)
#pragma unroll
        for (int q = 0; q < 4; ++q) {
            const int ml = i * 16 + l4 * 4 + q;
            rmax[i][q] = fmaxf(fmaxf(redM[0][ml], redM[1][ml]), fmaxf(redM[2][ml], redM[3][ml]));
        }
#pragma unroll
    for (int i = 0; i < 4; ++i)
#pragma unroll
        for (int q = 0; q < 4; ++q) {
            float sv = 0.f;
#pragma unroll
            for (int j = 0; j < 4; ++j) {
                const float e = __expf(acc1[i][j][q] - rmax[i][q]);
                acc1[i][j][q] = e;
                sv += e;
            }
#pragma unroll
            for (int off = 1; off <= 8; off <<= 1) sv += __shfl_xor(sv, off, 64);
            rsum[i][q] = sv;
        }
    if (l15 == 0) {
#pragma unroll
        for (int i = 0; i < 4; ++i)
#pragma unroll
            for (int q = 0; q < 4; ++q)
                redS[wid][i * 16 + l4 * 4 + q] = rsum[i][q];
    }
    __syncthreads();
#pragma unroll
    for (int i = 0; i < 4; ++i)
#pragma unroll
        for (int q = 0; q < 4; ++q) {
            const int ml = i * 16 + l4 * 4 + q;
            rsum[i][q] = redS[0][ml] + redS[1][ml] + redS[2][ml] + redS[3][ml];
        }
#pragma unroll
    for (int i = 0; i < 4; ++i)
#pragma unroll
        for (int q = 0; q < 4; ++q) {
            const float rinv = 1.f / rsum[i][q];
            const int ml = i * 16 + l4 * 4 + q;
#pragma unroll
            for (int j = 0; j < 4; ++j) {
                const int nc = j * 16 + l15;
                Pl[wid * 4096 + ml * 64 + (nc ^ SWZ(ml))] = f2bf(acc1[i][j][q] * rinv);
            }
        }
    __syncthreads();

    f32x4 accO[4][4] = {};
    for (int kc = 0; kc < 4; ++kc) {
        __syncthreads();
        stageB256(Vt + (long)(z * 256) * 256 + kc * 64, 256);
        __syncthreads();
#pragma unroll
        for (int i = 0; i < 4; ++i) {
            const bf16x8 a0 = fragP(kc, i, 0), a1 = fragP(kc, i, 1);
#pragma unroll
            for (int j = 0; j < 4; ++j) {
                accO[i][j] = __builtin_amdgcn_mfma_f32_16x16x32_bf16(a0, fragB(j, 0), accO[i][j], 0, 0, 0);
                accO[i][j] = __builtin_amdgcn_mfma_f32_16x16x32_bf16(a1, fragB(j, 1), accO[i][j], 0, 0, 0);
            }
        }
    }

#pragma unroll
    for (int i = 0; i < 4; ++i)
#pragma unroll
        for (int j = 0; j < 4; ++j) {
            const int d = wid * 64 + j * 16 + l15;
#pragma unroll
            for (int q = 0; q < 4; ++q) {
                const int mg = m0 + i * 16 + l4 * 4 + q;
                Oc[(long)(zb * 256 + mg) * 1024 + zn * 256 + d] = f2bf(accO[i][j][q]);
            }
        }
}

// ---------------- GLU gate + residual + LN (bf16 chain, 2 bf16 partials) ----------------
__global__ __launch_bounds__(256)
void glu_ln_k(const u16* __restrict__ xs0, const u16* __restrict__ g2,
              const float* __restrict__ gam, const float* __restrict__ bet,
              u16* __restrict__ outb)
{
    const int t = blockIdx.x, tid = threadIdx.x;
    const int f0 = tid * 4;
    const long PS = 8388608;
    const float4 xv = bf4f(*(const ushort4*)&xs0[(long)t * 1024 + f0]);
    const float4 a0 = bf4f(*(const ushort4*)&g2[(long)t * 2048 + f0]);
    const float4 g0 = bf4f(*(const ushort4*)&g2[(long)t * 2048 + 1024 + f0]);
    const float4 a1 = bf4f(*(const ushort4*)&g2[PS + (long)t * 2048 + f0]);
    const float4 g1 = bf4f(*(const ushort4*)&g2[PS + (long)t * 2048 + 1024 + f0]);
    const float ax = a0.x + a1.x, ay = a0.y + a1.y, az = a0.z + a1.z, aw = a0.w + a1.w;
    const float gx = g0.x + g1.x, gy = g0.y + g1.y, gz = g0.z + g1.z, gw = g0.w + g1.w;
    float vals[4];
    vals[0] = xv.x + ax / (1.f + expf(-gx));
    vals[1] = xv.y + ay / (1.f + expf(-gy));
    vals[2] = xv.z + az / (1.f + expf(-gz));
    vals[3] = xv.w + aw / (1.f + expf(-gw));
    float s1 = vals[0] + vals[1] + vals[2] + vals[3];
    float s2 = vals[0]*vals[0] + vals[1]*vals[1] + vals[2]*vals[2] + vals[3]*vals[3];
    block_red2(s1, s2, tid);
    const float mean = s1 * (1.f / 1024.f);
    const float var  = s2 * (1.f / 1024.f) - mean * mean;
    const float rstd = rsqrtf(var + EPSF);
    const float4 gm = *(const float4*)&gam[f0];
    const float4 bt = *(const float4*)&bet[f0];
    *(ushort4*)&outb[(long)t * 1024 + f0] = f4bf(
        (vals[0] - mean) * rstd * gm.x + bt.x,
        (vals[1] - mean) * rstd * gm.y + bt.y,
        (vals[2] - mean) * rstd * gm.z + bt.z,
        (vals[3] - mean) * rstd * gm.w + bt.w);
}

// ---------------- residual add + LN width 1024 (bf16 chain, P bf16 partials, opt bias) ----------------
template<int P, int BIAS>
__global__ __launch_bounds__(256)
void add_ln1024_k(const u16* __restrict__ A, const u16* __restrict__ Bp,
                  const float* __restrict__ bias,
                  const float* __restrict__ gam, const float* __restrict__ bet,
                  u16* __restrict__ outb)
{
    const int t = blockIdx.x, tid = threadIdx.x;
    const int f0 = tid * 4;
    const long PS = 4194304;
    const float4 a = bf4f(*(const ushort4*)&A[(long)t * 1024 + f0]);
    float4 b = bf4f(*(const ushort4*)&Bp[(long)t * 1024 + f0]);
#pragma unroll
    for (int p = 1; p < P; ++p) {
        const float4 bp = bf4f(*(const ushort4*)&Bp[p * PS + (long)t * 1024 + f0]);
        b.x += bp.x; b.y += bp.y; b.z += bp.z; b.w += bp.w;
    }
    if (BIAS) {
        const float4 bb = *(const float4*)&bias[f0];
        b.x += bb.x; b.y += bb.y; b.z += bb.z; b.w += bb.w;
    }
    float vals[4] = {a.x + b.x, a.y + b.y, a.z + b.z, a.w + b.w};
    float s1 = vals[0] + vals[1] + vals[2] + vals[3];
    float s2 = vals[0]*vals[0] + vals[1]*vals[1] + vals[2]*vals[2] + vals[3]*vals[3];
    block_red2(s1, s2, tid);
    const float mean = s1 * (1.f / 1024.f);
    const float var  = s2 * (1.f / 1024.f) - mean * mean;
    const float rstd = rsqrtf(var + EPSF);
    const float4 gm = *(const float4*)&gam[f0];
    const float4 bt = *(const float4*)&bet[f0];
    *(ushort4*)&outb[(long)t * 1024 + f0] = f4bf(
        (vals[0] - mean) * rstd * gm.x + bt.x,
        (vals[1] - mean) * rstd * gm.y + bt.y,
        (vals[2] - mean) * rstd * gm.z + bt.z,
        (vals[3] - mean) * rstd * gm.w + bt.w);
}

// ---------------- n2: LN(c1L(bf16) + pad(conv relu'd bf16)) width 4096 ----------------
__global__ __launch_bounds__(256)
void add_ln4096_k(const u16* __restrict__ A, const u16* __restrict__ C3,
                  const float* __restrict__ gam, const float* __restrict__ bet,
                  u16* __restrict__ outb)
{
    const int t = blockIdx.x, tid = threadIdx.x;
    const int f0 = tid * 16;
    float vals[16];
    const bf16x8 a0 = *(const bf16x8*)&A[(long)t * 4096 + f0];
    const bf16x8 a1 = *(const bf16x8*)&A[(long)t * 4096 + f0 + 8];
#pragma unroll
    for (int e = 0; e < 8; ++e) { vals[e] = bf2f((u16)a0[e]); vals[8 + e] = bf2f((u16)a1[e]); }
    if (tid < 64) {
        const bf16x8 b0 = *(const bf16x8*)&C3[(long)t * 1024 + f0];
        const bf16x8 b1 = *(const bf16x8*)&C3[(long)t * 1024 + f0 + 8];
#pragma unroll
        for (int e = 0; e < 8; ++e) { vals[e] += bf2f((u16)b0[e]); vals[8 + e] += bf2f((u16)b1[e]); }
    }
    float s1 = 0.f, s2 = 0.f;
#pragma unroll
    for (int e = 0; e < 16; ++e) { s1 += vals[e]; s2 += vals[e] * vals[e]; }
    block_red2(s1, s2, tid);
    const float mean = s1 * (1.f / 4096.f);
    const float var  = s2 * (1.f / 4096.f) - mean * mean;
    const float rstd = rsqrtf(var + EPSF);
#pragma unroll
    for (int c = 0; c < 4; ++c) {
        const int fc = f0 + c * 4;
        const float4 gm = *(const float4*)&gam[fc];
        const float4 bt = *(const float4*)&bet[fc];
        *(ushort4*)&outb[(long)t * 4096 + fc] = f4bf(
            (vals[c*4+0] - mean) * rstd * gm.x + bt.x,
            (vals[c*4+1] - mean) * rstd * gm.y + bt.y,
            (vals[c*4+2] - mean) * rstd * gm.z + bt.z,
            (vals[c*4+3] - mean) * rstd * gm.w + bt.w);
    }
}

// ---------------- depthwise conv width-9, 8 channels/thread ----------------
__global__ __launch_bounds__(256)
void dwconv8_k(const u16* __restrict__ h, const float* __restrict__ wT,
               u16* __restrict__ out)
{
    const long idx = (long)blockIdx.x * 256 + threadIdx.x;
    const int cg = (int)(idx & 511);
    const int t  = (int)(idx >> 9);
    const int w  = t & 255;
    const int c0 = cg * 8;
    float acc[8] = {};
#pragma unroll
    for (int k = 0; k < 9; ++k) {
        const int wp = w + k - 4;
        if ((unsigned)wp < 256u) {
            const bf16x8 hv = *(const bf16x8*)&h[(long)(t + k - 4) * 4096 + c0];
            const float4 w0 = *(const float4*)&wT[k * 4096 + c0];
            const float4 w1 = *(const float4*)&wT[k * 4096 + c0 + 4];
            acc[0] += bf2f((u16)hv[0]) * w0.x;
            acc[1] += bf2f((u16)hv[1]) * w0.y;
            acc[2] += bf2f((u16)hv[2]) * w0.z;
            acc[3] += bf2f((u16)hv[3]) * w0.w;
            acc[4] += bf2f((u16)hv[4]) * w1.x;
            acc[5] += bf2f((u16)hv[5]) * w1.y;
            acc[6] += bf2f((u16)hv[6]) * w1.z;
            acc[7] += bf2f((u16)hv[7]) * w1.w;
        }
    }
    bf16x8 res;
#pragma unroll
    for (int j = 0; j < 8; ++j) res[j] = (short)f2bf(acc[j]);
    *(bf16x8*)&out[(long)t * 4096 + c0] = res;
}

// ---------------- final transpose: bf16 (tokens,1024) -> f32 (B,1,1024,256) ----------------
__global__ __launch_bounds__(256)
void transpose_out_k(const u16* __restrict__ xs, float* __restrict__ out)
{
    __shared__ u16 tile[32][34];
    const int b = blockIdx.z, f0 = blockIdx.y * 32, w0 = blockIdx.x * 32;
    const int tid = threadIdx.x, c = tid & 31, r = tid >> 5;
#pragma unroll
    for (int it = 0; it < 4; ++it) {
        const int w = w0 + r + it * 8;
        tile[r + it * 8][c] = xs[((long)b * 256 + w) * 1024 + f0 + c];
    }
    __syncthreads();
#pragma unroll
    for (int it = 0; it < 4; ++it) {
        const int fl = r + it * 8;
        out[((long)b * 1024 + f0 + fl) * 256 + w0 + c] = bf2f(tile[c][fl]);
    }
}

// =======================================================================
extern "C" void kernel_launch(void* const* d_in, const int* in_sizes, int n_in,
                              void* d_out, int out_size, void* d_ws, size_t ws_size,
                              hipStream_t stream)
{
    const float* x      = (const float*)d_in[0];
    const float* bott_w = (const float*)d_in[1];
    const float* bn_g   = (const float*)d_in[2];
    const float* bn_b   = (const float*)d_in[3];
    const float* bn_m   = (const float*)d_in[4];
    const float* bn_v   = (const float*)d_in[5];
    const float* glu_w  = (const float*)d_in[6];
    const float* n1g    = (const float*)d_in[7];
    const float* n1b    = (const float*)d_in[8];
    const float* c1L_w  = (const float*)d_in[9];
    const float* c1R_w  = (const float*)d_in[10];
    const float* n2g    = (const float*)d_in[11];
    const float* n2b    = (const float*)d_in[12];
    const float* c2dw_w = (const float*)d_in[13];
    const float* c2pw_w = (const float*)d_in[14];
    const float* n3g    = (const float*)d_in[15];
    const float* n3b    = (const float*)d_in[16];
    const float* qw     = (const float*)d_in[17];
    const float* qb     = (const float*)d_in[18];
    const float* kw     = (const float*)d_in[19];
    const float* kb     = (const float*)d_in[20];
    const float* vw     = (const float*)d_in[21];
    const float* vb     = (const float*)d_in[22];
    const float* ow     = (const float*)d_in[23];
    const float* ob     = (const float*)d_in[24];
    const float* er     = (const float*)d_in[25];
    const float* dist_w = (const float*)d_in[26];
    const float* n4g    = (const float*)d_in[27];
    const float* n4b    = (const float*)d_in[28];
    const float* c3_w   = (const float*)d_in[29];
    const float* c4_w   = (const float*)d_in[30];
    const float* n5g    = (const float*)d_in[31];
    const float* n5b    = (const float*)d_in[32];
    float* out = (float*)d_out;

    // ---- workspace layout (MiB offsets, bf16 residual chain) ----
    char* Wb_ = (char*)d_ws;
    auto Bf = [&](size_t mib) { return (u16*)(Wb_ + (mib << 20)); };
    u16* XA   = Bf(0);
    u16* XB   = Bf(8);
    u16* H0b  = Bf(32);
    u16* Hglu = Bf(64);
    u16* C3s  = Bf(64);   // conv relu'd out (8 MB), stages 4-6
    u16* P4   = Bf(64);   // c2pw/O-proj/c4 4 bf16 partials (from stage 8)
    u16* H1b  = Bf(128);
    u16* Hdw  = Bf(160);
    u16* QKVb = Bf(192);
    u16* Vt   = Bf(216);
    u16* S1b  = Bf(264);
    u16* wGLU = Bf(296); u16* wC1L = Bf(300); u16* wC1R = Bf(308);
    u16* wC2P = Bf(314); u16* wQKV = Bf(322); u16* wO   = Bf(328);
    u16* wC3  = Bf(330); u16* wC4  = Bf(338);
    u16* erT  = Bf(346);
    u16* zp   = (u16*)(Wb_ + (346u << 20) + 131072);
    float* wdwT = (float*)(Wb_ + (346u << 20) + 131072 + 16384);
    float* bQKV = (float*)(Wb_ + (346u << 20) + 131072 + 16384 + 147456);

    const dim3 blk(256);
    const dim3 blk8(512);
    const long PS1 = 4194304;
    const size_t SH8 = 131072;

    // 0. merged setup (one launch); kw/kb pre-scaled by 1/32
    SetupArgs sa;
    sa.ws[0] = glu_w;  sa.wd[0] = wGLU;            sa.wn[0] = 524288;
    sa.ws[1] = c1L_w;  sa.wd[1] = wC1L;            sa.wn[1] = 1048576;
    sa.ws[2] = c2pw_w; sa.wd[2] = wC2P;            sa.wn[2] = 1048576;
    sa.ws[3] = c3_w;   sa.wd[3] = wC3;             sa.wn[3] = 1048576;
    sa.ws[4] = c4_w;   sa.wd[4] = wC4;             sa.wn[4] = 1048576;
    sa.ws[5] = qw;     sa.wd[5] = wQKV;            sa.wn[5] = 262144;
    sa.ws[6] = kw;     sa.wd[6] = wQKV + 1048576;  sa.wn[6] = 262144;
    sa.ws[7] = vw;     sa.wd[7] = wQKV + 2097152;  sa.wn[7] = 262144;
    sa.ws[8] = ow;     sa.wd[8] = wO;              sa.wn[8] = 262144;
    sa.c1r = c1R_w; sa.c1rd = wC1R;
    sa.er  = er;    sa.erd  = erT;
    sa.dw  = c2dw_w; sa.dwd = wdwT;
    sa.qb = qb; sa.kb = kb; sa.vb = vb; sa.bcat = bQKV;
    sa.zp = zp;
    {
        int bc[14] = {2048, 4096, 4096, 4096, 4096, 1024, 1024, 1024, 1024,
                      12288, 256, 144, 12, 32};
        int acc = 0;
        for (int s = 0; s < 14; ++s) { sa.off[s] = acc; acc += bc[s]; }
        sa.off[14] = acc;
        setup_k<<<dim3(acc), blk, 0, stream>>>(sa);
    }

    // 1. bottleneck + BN + ReLU + transpose -> XA (xs0, bf16)
    bottleneck_k<<<dim3(8, 32, 16), blk, 0, stream>>>(x, bott_w, bn_g, bn_b, bn_m, bn_v, XA);

    // 2. GLU matmul, split-K=2 -> Hglu bf16 partials
    gemm8_k<0,0,0,2,0><<<dim3(8, 16, 2), blk8, SH8, stream>>>(XA, wGLU, nullptr, Hglu,
        2048, 512, 1024, 1024, (long)4096 * 2048, nullptr);

    // 3. n1: LN(xs0 + a*sigmoid(g)) -> XB (xs1)
    glu_ln_k<<<dim3(4096), blk, 0, stream>>>(XA, Hglu, n1g, n1b, XB);

    // 4+5. merged c1L (relu -> H0b) + conv1R K'=3072 (relu -> C3s), one launch
    ffconv8_k<<<dim3(20, 16), blk8, SH8, stream>>>(XB, wC1L, wC1R, zp, H0b, C3s);

    // 6. n2: LN(H0b + pad(C3s)) -> H1b bf16
    add_ln4096_k<<<dim3(4096), blk, 0, stream>>>(H0b, C3s, n2g, n2b, H1b);

    // 7. depthwise conv9 (vectorized x8): H1b -> Hdw
    dwconv8_k<<<dim3(8192), blk, 0, stream>>>(H1b, wdwT, Hdw);

    // 8. c2pw, split-K=4 -> P4 bf16 partials
    gemm8_k<0,0,0,4,0><<<dim3(4, 16, 4), blk8, SH8, stream>>>(Hdw, wC2P, nullptr, P4,
        1024, 1024, 4096, 4096, PS1, nullptr);

    // 9. n3: LN(xs1 + sum P4) -> XA (xs2)
    add_ln1024_k<4,0><<<dim3(4096), blk, 0, stream>>>(XB, P4, nullptr, n3g, n3b, XA);

    // 10. fused QKV projection; V-tiles written transposed to Vt in-epilogue
    gemm8_k<0,1,1,1,1><<<dim3(12, 16, 1), blk8, SH8, stream>>>(XA, wQKV, bQKV, QKVb,
        3072, 1024, 1024, 1024, 0, Vt);

    // 11. fused attention: K=512 concat scores + softmax + PV -> S1b
    attn_fused_k<<<dim3(4, 64), blk, 0, stream>>>(QKVb, erT, Vt, dist_w, S1b);

    // 12. output projection, split-K=4 -> P4 bf16 partials (bias added in n4)
    gemm8_k<0,0,0,4,0><<<dim3(4, 16, 4), blk8, SH8, stream>>>(S1b, wO, nullptr, P4,
        1024, 256, 1024, 1024, PS1, nullptr);

    // 13. n4: LN(xs2 + sum P4 + ob) -> XB (xs3)
    add_ln1024_k<4,1><<<dim3(4096), blk, 0, stream>>>(XA, P4, ob, n4g, n4b, XB);

    // 14. c3: relu -> H0b bf16
    gemm8_k<1,1,0,1,0><<<dim3(16, 16, 1), blk8, SH8, stream>>>(XB, wC3, nullptr, H0b,
        4096, 1024, 1024, 1024, 0, nullptr);

    // 15. c4, split-K=4 -> P4 bf16 partials
    gemm8_k<0,0,0,4,0><<<dim3(4, 16, 4), blk8, SH8, stream>>>(H0b, wC4, nullptr, P4,
        1024, 1024, 4096, 4096, PS1, nullptr);

    // 16. n5: LN(xs3 + sum P4) -> XA (xs4, bf16)
    add_ln1024_k<4,0><<<dim3(4096), blk, 0, stream>>>(XB, P4, nullptr, n5g, n5b, XA);

    // 17. transpose to (B, 1, 1024, 256) f32
    transpose_out_k<<<dim3(8, 32, 16), blk, 0, stream>>>(XA, out);

    (void)in_sizes; (void)n_in; (void)out_size; (void)ws_size;
}

// Round 14
// 464.106 us; speedup vs baseline: 1.1037x; 1.1037x over previous
//
#include <hip/hip_runtime.h>
#include <hip/hip_bf16.h>

// FrameTransformer: B=16, C=8, BINS=1024, W=256, FF=2048, NB=4
// tokens = B*W = 4096, feature width 1024, FF width 4096, head dim 256.
#define EPSF 1e-5f

typedef unsigned short u16;
typedef unsigned int   u32;
typedef __attribute__((ext_vector_type(8))) short bf16x8;
typedef __attribute__((ext_vector_type(4))) float f32x4;

// 3-bit XOR swizzle for 64-elem (128 B) LDS rows.
#define SWZ(row) (((row) & 7) << 3)

__device__ __forceinline__ u16 f2bf(float f) {
    u32 u = __builtin_bit_cast(u32, f);
    u32 r = u + 0x7fffu + ((u >> 16) & 1u);
    return (u16)(r >> 16);
}
__device__ __forceinline__ float bf2f(u16 h) {
    return __builtin_bit_cast(float, (u32)h << 16);
}
__device__ __forceinline__ float4 bf4f(ushort4 v) {
    return make_float4(bf2f(v.x), bf2f(v.y), bf2f(v.z), bf2f(v.w));
}
__device__ __forceinline__ ushort4 f4bf(float a, float b, float c, float d) {
    ushort4 o; o.x = f2bf(a); o.y = f2bf(b); o.z = f2bf(c); o.w = f2bf(d); return o;
}
__device__ __forceinline__ void gld16(void* lds, const void* gsrc) {
    __builtin_amdgcn_global_load_lds(
        (const __attribute__((address_space(1))) u32*)gsrc,
        (__attribute__((address_space(3))) u32*)lds, 16, 0, 0);
}

__device__ __forceinline__ float wred_sum(float v) {
#pragma unroll
    for (int off = 32; off; off >>= 1) v += __shfl_xor(v, off, 64);
    return v;
}
__device__ __forceinline__ void block_red2(float& s1, float& s2, int tid) {
    __shared__ float red[8];
    s1 = wred_sum(s1); s2 = wred_sum(s2);
    const int lane = tid & 63, wid = tid >> 6;
    if (!lane) { red[wid] = s1; red[4 + wid] = s2; }
    __syncthreads();
    s1 = red[0] + red[1] + red[2] + red[3];
    s2 = red[4] + red[5] + red[6] + red[7];
}

// ---------------- merged setup: all weight conversions in one launch ----------------
// kw (seg 6) and kb (bias middle third) pre-scaled by 1/32 (skew fold).
struct SetupArgs {
    const float* ws[9]; u16* wd[9]; int wn[9];
    const float* c1r; u16* c1rd;
    const float* er;  u16* erd;
    const float* dw;  float* dwd;
    const float* qb;  const float* kb; const float* vb; float* bcat;
    u16* zp;
    int off[15];
};
__global__ __launch_bounds__(256)
void setup_k(SetupArgs a)
{
    const int b = blockIdx.x;
    int seg = 0;
    while (seg < 13 && b >= a.off[seg + 1]) ++seg;
    const int i = (b - a.off[seg]) * 256 + threadIdx.x;
    if (seg < 9) {
        if (i < a.wn[seg]) {
            const float4 v = ((const float4*)a.ws[seg])[i];
            const float s = (seg == 6) ? 0.03125f : 1.f;
            ((ushort4*)a.wd[seg])[i] = f4bf(v.x * s, v.y * s, v.z * s, v.w * s);
        }
    } else if (seg == 9) {
        if (i < 3145728) {
            const int q = i / 3072, rem = i - q * 3072;
            const int ks = rem >> 10, ci = rem & 1023;
            a.c1rd[i] = f2bf(a.c1r[((long)q * 1024 + ci) * 3 + ks]);
        }
    } else if (seg == 10) {
        if (i < 65536) { const int c = i >> 8, d = i & 255; a.erd[i] = f2bf(a.er[d * 256 + c]); }
    } else if (seg == 11) {
        if (i < 36864) { const int k = i >> 12, c = i & 4095; a.dwd[i] = a.dw[c * 9 + k]; }
    } else if (seg == 12) {
        if (i < 3072) {
            const float* s = (i < 1024) ? a.qb : ((i < 2048) ? a.kb : a.vb);
            float v = s[i & 1023];
            if (i >= 1024 && i < 2048) v *= 0.03125f;
            a.bcat[i] = v;
        }
    } else {
        if (i < 8192) a.zp[i] = 0;
    }
}

// ---------------- stage 1: bottleneck 1x1 conv + BN + ReLU + transpose (bf16 out) ----------------
// float4-vectorized x loads: thread (tw=tid&7, th=tid>>3) covers 4 w at row th.
__global__ __launch_bounds__(256)
void bottleneck_k(const float* __restrict__ x, const float* __restrict__ bw,
                  const float* __restrict__ bn_g, const float* __restrict__ bn_b,
                  const float* __restrict__ bn_m, const float* __restrict__ bn_v,
                  u16* __restrict__ xsb)
{
    __shared__ float tile[32][33];
    const int b = blockIdx.z, h0 = blockIdx.y * 32, w0 = blockIdx.x * 32;
    const int tid = threadIdx.x;
    const int tw = tid & 7, th = tid >> 3;            // 8 w-groups x 32 h-rows
    float wreg[8];
#pragma unroll
    for (int ch = 0; ch < 8; ++ch) wreg[ch] = bw[ch];
    const float sc = bn_g[0] * rsqrtf(bn_v[0] + EPSF);
    const float sh = bn_b[0] - bn_m[0] * sc;
    float4 acc = make_float4(0.f, 0.f, 0.f, 0.f);
#pragma unroll
    for (int ch = 0; ch < 8; ++ch) {
        const float4 v = *(const float4*)&x[(((long)b * 8 + ch) * 1024 + h0 + th) * 256 + w0 + tw * 4];
        acc.x += v.x * wreg[ch]; acc.y += v.y * wreg[ch];
        acc.z += v.z * wreg[ch]; acc.w += v.w * wreg[ch];
    }
    tile[th][tw * 4 + 0] = fmaxf(acc.x * sc + sh, 0.f);
    tile[th][tw * 4 + 1] = fmaxf(acc.y * sc + sh, 0.f);
    tile[th][tw * 4 + 2] = fmaxf(acc.z * sc + sh, 0.f);
    tile[th][tw * 4 + 3] = fmaxf(acc.w * sc + sh, 0.f);
    __syncthreads();
    const int c = tid & 31, r = tid >> 5;
#pragma unroll
    for (int it = 0; it < 4; ++it) {
        const int wl = r + it * 8;
        xsb[((long)b * 256 + w0 + wl) * 1024 + h0 + c] = f2bf(tile[c][wl]);
    }
}

// ============ 8-phase 256x256 bf16 MFMA GEMM (T2+T3+T4+T5) ============
// VOUT: for N-tiles with n0>=2048 (V region of fused QKV), write the output
// transposed per head into Vtp[(z*256+d)*256+w] instead of Cout.
template<int ACT, int OUTBF, int BIAS, int SPLITK, int VOUT>
__global__ __launch_bounds__(512, 2)
void gemm8_k(const u16* __restrict__ A, const u16* __restrict__ B,
             const float* __restrict__ bias, void* __restrict__ Cout,
             int N, int K /*per slice*/, int lda, int ldb, long partStride,
             u16* __restrict__ Vtp)
{
    extern __shared__ u16 lds[];
    const int m0 = blockIdx.y * 256, n0 = blockIdx.x * 256;
    const int koff = (SPLITK > 1) ? blockIdx.z * K : 0;
    const int nt = K >> 6;
    const int tid = threadIdx.x;
    const int lane = tid & 63, wid = tid >> 6;
    const int wr = ((wid >> 2) & 1) * 128;
    const int wc = (wid & 3) * 64;
    const int l15 = lane & 15, l4 = lane >> 4;

    const u16* Ag = A + (long)m0 * lda + koff;
    const u16* Bg = B + (long)n0 * ldb + koff;

    auto stage = [&](const u16* g, int ld, int ldsbase, int kcol, int h) {
#pragma unroll
        for (int is = 0; is < 2; ++is) {
            const int r = h * 128 + is * 64 + (tid >> 3);
            const int sc = ((tid & 7) * 8) ^ SWZ(r);
            gld16(&lds[ldsbase + h * 8192 + is * 4096 + tid * 8],
                  g + (long)r * ld + kcol + sc);
        }
    };
    auto frag = [&](int base, int row, int col) -> bf16x8 {
        return *(const bf16x8*)&lds[base + row * 64 + (col ^ SWZ(row))];
    };

    f32x4 acc[8][4] = {};

    stage(Ag, lda, 0, 0, 0);
    stage(Ag, lda, 0, 0, 1);
    stage(Bg, ldb, 32768, 0, 0);
    stage(Bg, ldb, 32768, 0, 1);
    if (nt > 1) {
        stage(Bg, ldb, 49152, 64, 0);
        stage(Bg, ldb, 49152, 64, 1);
        stage(Ag, lda, 16384, 64, 0);
        asm volatile("s_waitcnt vmcnt(6)" ::: "memory");
    } else {
        asm volatile("s_waitcnt vmcnt(0)" ::: "memory");
    }
    __builtin_amdgcn_s_barrier();

    for (int kt = 0; kt < nt; ++kt) {
        const int cs = kt & 1;
        const int ab = cs * 16384;
        const int bb = 32768 + cs * 16384;
        const int abn = (cs ^ 1) * 16384;
        const int kc1 = (kt + 1) * 64, kc2 = (kt + 2) * 64;
        bf16x8 alo[4][2], ahi[4][2], b01[2][2], b23[2][2];

#pragma unroll
        for (int i = 0; i < 4; ++i)
#pragma unroll
            for (int kk = 0; kk < 2; ++kk)
                alo[i][kk] = frag(ab, wr + i * 16 + l15, kk * 32 + l4 * 8);
#pragma unroll
        for (int j = 0; j < 2; ++j)
#pragma unroll
            for (int kk = 0; kk < 2; ++kk)
                b01[j][kk] = frag(bb, wc + j * 16 + l15, kk * 32 + l4 * 8);
        if (kt + 1 < nt) stage(Ag, lda, abn, kc1, 1);
        __builtin_amdgcn_s_barrier();
        asm volatile("s_waitcnt lgkmcnt(0)" ::: "memory");
        __builtin_amdgcn_s_setprio(1);
#pragma unroll
        for (int i = 0; i < 4; ++i)
#pragma unroll
            for (int j = 0; j < 2; ++j)
#pragma unroll
                for (int kk = 0; kk < 2; ++kk)
                    acc[i][j] = __builtin_amdgcn_mfma_f32_16x16x32_bf16(alo[i][kk], b01[j][kk], acc[i][j], 0, 0, 0);
        __builtin_amdgcn_s_setprio(0);
        __builtin_amdgcn_s_barrier();

#pragma unroll
        for (int j = 0; j < 2; ++j)
#pragma unroll
            for (int kk = 0; kk < 2; ++kk)
                b23[j][kk] = frag(bb, wc + (j + 2) * 16 + l15, kk * 32 + l4 * 8);
        if (kt + 2 < nt) stage(Bg, ldb, bb, kc2, 0);
        __builtin_amdgcn_s_barrier();
        asm volatile("s_waitcnt lgkmcnt(0)" ::: "memory");
        __builtin_amdgcn_s_setprio(1);
#pragma unroll
        for (int i = 0; i < 4; ++i)
#pragma unroll
            for (int j = 0; j < 2; ++j)
#pragma unroll
                for (int kk = 0; kk < 2; ++kk)
                    acc[i][j + 2] = __builtin_amdgcn_mfma_f32_16x16x32_bf16(alo[i][kk], b23[j][kk], acc[i][j + 2], 0, 0, 0);
        __builtin_amdgcn_s_setprio(0);
        __builtin_amdgcn_s_barrier();

#pragma unroll
        for (int i = 0; i < 4; ++i)
#pragma unroll
            for (int kk = 0; kk < 2; ++kk)
                ahi[i][kk] = frag(ab, wr + (i + 4) * 16 + l15, kk * 32 + l4 * 8);
        if (kt + 2 < nt) stage(Bg, ldb, bb, kc2, 1);
        __builtin_amdgcn_s_barrier();
        asm volatile("s_waitcnt lgkmcnt(0)" ::: "memory");
        __builtin_amdgcn_s_setprio(1);
#pragma unroll
        for (int i = 0; i < 4; ++i)
#pragma unroll
            for (int j = 0; j < 2; ++j)
#pragma unroll
                for (int kk = 0; kk < 2; ++kk)
                    acc[i + 4][j + 2] = __builtin_amdgcn_mfma_f32_16x16x32_bf16(ahi[i][kk], b23[j][kk], acc[i + 4][j + 2], 0, 0, 0);
        __builtin_amdgcn_s_setprio(0);
        __builtin_amdgcn_s_barrier();

        if (kt + 2 < nt) stage(Ag, lda, ab, kc2, 0);
        __builtin_amdgcn_s_barrier();
        __builtin_amdgcn_s_setprio(1);
#pragma unroll
        for (int i = 0; i < 4; ++i)
#pragma unroll
            for (int j = 0; j < 2; ++j)
#pragma unroll
                for (int kk = 0; kk < 2; ++kk)
                    acc[i + 4][j] = __builtin_amdgcn_mfma_f32_16x16x32_bf16(ahi[i][kk], b01[j][kk], acc[i + 4][j], 0, 0, 0);
        __builtin_amdgcn_s_setprio(0);
        if (kt + 2 < nt) {
            asm volatile("s_waitcnt vmcnt(6)" ::: "memory");
        } else {
            asm volatile("s_waitcnt vmcnt(0)" ::: "memory");
        }
        __builtin_amdgcn_s_barrier();
    }

    if (VOUT && n0 >= 2048) {
        // V region of fused QKV: write transposed per head.
        const int zb4 = (m0 >> 8) * 4;
#pragma unroll
        for (int i = 0; i < 8; ++i)
#pragma unroll
            for (int j = 0; j < 4; ++j) {
                const int n = n0 + wc + j * 16 + l15;
                const int d = n - 2048, zn = d >> 8, dl = d & 255;
                const float bv = BIAS ? bias[n] : 0.f;
                const int w = wr + i * 16 + l4 * 4;
                ushort4 st = f4bf(acc[i][j][0] + bv, acc[i][j][1] + bv,
                                  acc[i][j][2] + bv, acc[i][j][3] + bv);
                *(ushort4*)&Vtp[((long)(zb4 + zn) * 256 + dl) * 256 + w] = st;
            }
    } else if (SPLITK > 1) {
        u16* Cp = (u16*)Cout + (long)blockIdx.z * partStride;
#pragma unroll
        for (int i = 0; i < 8; ++i)
#pragma unroll
            for (int j = 0; j < 4; ++j) {
                const int n = n0 + wc + j * 16 + l15;
#pragma unroll
                for (int q = 0; q < 4; ++q) {
                    const int m = m0 + wr + i * 16 + l4 * 4 + q;
                    Cp[(long)m * N + n] = f2bf(acc[i][j][q]);
                }
            }
    } else {
        float* Cf = (float*)Cout;
        u16*   Cb = (u16*)Cout;
#pragma unroll
        for (int i = 0; i < 8; ++i)
#pragma unroll
            for (int j = 0; j < 4; ++j) {
                const int n = n0 + wc + j * 16 + l15;
                const float bv = BIAS ? bias[n] : 0.f;
#pragma unroll
                for (int q = 0; q < 4; ++q) {
                    const int m = m0 + wr + i * 16 + l4 * 4 + q;
                    float v = acc[i][j][q] + bv;
                    if (ACT) v = fmaxf(v, 0.f);
                    if (OUTBF) Cb[(long)m * N + n] = f2bf(v);
                    else       Cf[(long)m * N + n] = v;
                }
            }
    }
}

// ============ merged c1L + conv1R launch (8-phase body, K=1024, nt=16) ============
// bx<16: c1L N-tile (relu -> Hout N=4096). bx>=16: conv tap=(bx-16)/4,
// ncol=(bx-16)&3; shifted-A, bf16 partial out to Cp3 + tap*4M. Uniform nt=16.
__global__ __launch_bounds__(512, 2)
void ffconv8_k(const u16* __restrict__ Xb, const u16* __restrict__ Wl,
               const u16* __restrict__ Wr, const u16* __restrict__ zp,
               u16* __restrict__ Hout, u16* __restrict__ Cp3)
{
    extern __shared__ u16 lds[];
    const int bx = blockIdx.x;
    const int m0 = blockIdx.y * 256;
    const bool conv = bx >= 16;
    const int tap  = conv ? ((bx - 16) >> 2) : 0;
    const int shift = conv ? (tap - 1) : 0;
    const int n0 = conv ? (((bx - 16) & 3) * 256) : (bx * 256);
    const u16* Bbase = conv ? (Wr + (long)n0 * 3072 + tap * 1024)
                            : (Wl + (long)n0 * 1024);
    const int ldb = conv ? 3072 : 1024;
    const int nt = 16;
    const int tid = threadIdx.x;
    const int lane = tid & 63, wid = tid >> 6;
    const int wr = ((wid >> 2) & 1) * 128;
    const int wc = (wid & 3) * 64;
    const int l15 = lane & 15, l4 = lane >> 4;

    auto stageA = [&](int ldsbase, int kcol, int h) {
#pragma unroll
        for (int is = 0; is < 2; ++is) {
            const int r = h * 128 + is * 64 + (tid >> 3);
            const int sc = ((tid & 7) * 8) ^ SWZ(r);
            const int t = m0 + r;
            const int wp = (t & 255) + shift;
            const u16* src = ((unsigned)wp < 256u)
                ? Xb + (long)(t + shift) * 1024 + kcol + sc
                : zp;
            gld16(&lds[ldsbase + h * 8192 + is * 4096 + tid * 8], src);
        }
    };
    auto stageB = [&](int ldsbase, int kcol, int h) {
#pragma unroll
        for (int is = 0; is < 2; ++is) {
            const int r = h * 128 + is * 64 + (tid >> 3);
            const int sc = ((tid & 7) * 8) ^ SWZ(r);
            gld16(&lds[ldsbase + h * 8192 + is * 4096 + tid * 8],
                  Bbase + (long)r * ldb + kcol + sc);
        }
    };
    auto frag = [&](int base, int row, int col) -> bf16x8 {
        return *(const bf16x8*)&lds[base + row * 64 + (col ^ SWZ(row))];
    };

    f32x4 acc[8][4] = {};

    stageA(0, 0, 0);
    stageA(0, 0, 1);
    stageB(32768, 0, 0);
    stageB(32768, 0, 1);
    stageB(49152, 64, 0);
    stageB(49152, 64, 1);
    stageA(16384, 64, 0);
    asm volatile("s_waitcnt vmcnt(6)" ::: "memory");
    __builtin_amdgcn_s_barrier();

    for (int kt = 0; kt < nt; ++kt) {
        const int cs = kt & 1;
        const int ab = cs * 16384;
        const int bb = 32768 + cs * 16384;
        const int abn = (cs ^ 1) * 16384;
        const int kc1 = (kt + 1) * 64, kc2 = (kt + 2) * 64;
        bf16x8 alo[4][2], ahi[4][2], b01[2][2], b23[2][2];

#pragma unroll
        for (int i = 0; i < 4; ++i)
#pragma unroll
            for (int kk = 0; kk < 2; ++kk)
                alo[i][kk] = frag(ab, wr + i * 16 + l15, kk * 32 + l4 * 8);
#pragma unroll
        for (int j = 0; j < 2; ++j)
#pragma unroll
            for (int kk = 0; kk < 2; ++kk)
                b01[j][kk] = frag(bb, wc + j * 16 + l15, kk * 32 + l4 * 8);
        if (kt + 1 < nt) stageA(abn, kc1, 1);
        __builtin_amdgcn_s_barrier();
        asm volatile("s_waitcnt lgkmcnt(0)" ::: "memory");
        __builtin_amdgcn_s_setprio(1);
#pragma unroll
        for (int i = 0; i < 4; ++i)
#pragma unroll
            for (int j = 0; j < 2; ++j)
#pragma unroll
                for (int kk = 0; kk < 2; ++kk)
                    acc[i][j] = __builtin_amdgcn_mfma_f32_16x16x32_bf16(alo[i][kk], b01[j][kk], acc[i][j], 0, 0, 0);
        __builtin_amdgcn_s_setprio(0);
        __builtin_amdgcn_s_barrier();

#pragma unroll
        for (int j = 0; j < 2; ++j)
#pragma unroll
            for (int kk = 0; kk < 2; ++kk)
                b23[j][kk] = frag(bb, wc + (j + 2) * 16 + l15, kk * 32 + l4 * 8);
        if (kt + 2 < nt) stageB(bb, kc2, 0);
        __builtin_amdgcn_s_barrier();
        asm volatile("s_waitcnt lgkmcnt(0)" ::: "memory");
        __builtin_amdgcn_s_setprio(1);
#pragma unroll
        for (int i = 0; i < 4; ++i)
#pragma unroll
            for (int j = 0; j < 2; ++j)
#pragma unroll
                for (int kk = 0; kk < 2; ++kk)
                    acc[i][j + 2] = __builtin_amdgcn_mfma_f32_16x16x32_bf16(alo[i][kk], b23[j][kk], acc[i][j + 2], 0, 0, 0);
        __builtin_amdgcn_s_setprio(0);
        __builtin_amdgcn_s_barrier();

#pragma unroll
        for (int i = 0; i < 4; ++i)
#pragma unroll
            for (int kk = 0; kk < 2; ++kk)
                ahi[i][kk] = frag(ab, wr + (i + 4) * 16 + l15, kk * 32 + l4 * 8);
        if (kt + 2 < nt) stageB(bb, kc2, 1);
        __builtin_amdgcn_s_barrier();
        asm volatile("s_waitcnt lgkmcnt(0)" ::: "memory");
        __builtin_amdgcn_s_setprio(1);
#pragma unroll
        for (int i = 0; i < 4; ++i)
#pragma unroll
            for (int j = 0; j < 2; ++j)
#pragma unroll
                for (int kk = 0; kk < 2; ++kk)
                    acc[i + 4][j + 2] = __builtin_amdgcn_mfma_f32_16x16x32_bf16(ahi[i][kk], b23[j][kk], acc[i + 4][j + 2], 0, 0, 0);
        __builtin_amdgcn_s_setprio(0);
        __builtin_amdgcn_s_barrier();

        if (kt + 2 < nt) stageA(ab, kc2, 0);
        __builtin_amdgcn_s_barrier();
        __builtin_amdgcn_s_setprio(1);
#pragma unroll
        for (int i = 0; i < 4; ++i)
#pragma unroll
            for (int j = 0; j < 2; ++j)
#pragma unroll
                for (int kk = 0; kk < 2; ++kk)
                    acc[i + 4][j] = __builtin_amdgcn_mfma_f32_16x16x32_bf16(ahi[i][kk], b01[j][kk], acc[i + 4][j], 0, 0, 0);
        __builtin_amdgcn_s_setprio(0);
        if (kt + 2 < nt) {
            asm volatile("s_waitcnt vmcnt(6)" ::: "memory");
        } else {
            asm volatile("s_waitcnt vmcnt(0)" ::: "memory");
        }
        __builtin_amdgcn_s_barrier();
    }

    if (conv) {
        u16* Cp = Cp3 + (long)tap * 4194304;
#pragma unroll
        for (int i = 0; i < 8; ++i)
#pragma unroll
            for (int j = 0; j < 4; ++j) {
                const int n = n0 + wc + j * 16 + l15;
#pragma unroll
                for (int q = 0; q < 4; ++q) {
                    const int m = m0 + wr + i * 16 + l4 * 4 + q;
                    Cp[(long)m * 1024 + n] = f2bf(acc[i][j][q]);
                }
            }
    } else {
#pragma unroll
        for (int i = 0; i < 8; ++i)
#pragma unroll
            for (int j = 0; j < 4; ++j) {
                const int n = n0 + wc + j * 16 + l15;
#pragma unroll
                for (int q = 0; q < 4; ++q) {
                    const int m = m0 + wr + i * 16 + l4 * 4 + q;
                    Hout[(long)m * 4096 + n] = f2bf(fmaxf(acc[i][j][q], 0.f));
                }
            }
    }
}

// ============ fused attention: one K=512 concat score GEMM -> softmax -> PV ============
__global__ __launch_bounds__(256, 2)
void attn_fused_k(const u16* __restrict__ QKVb, const u16* __restrict__ erT,
                  const u16* __restrict__ Vt, const float* __restrict__ dwp,
                  u16* __restrict__ Oc)
{
    __shared__ __align__(16) u16 As[4096];
    __shared__ __align__(16) u16 Bs[16384];
    __shared__ __align__(16) u16 Pl[16384];
    __shared__ float redM[4][64];
    __shared__ float redS[4][64];
    const int z = blockIdx.y, zb = z >> 2, zn = z & 3;
    const int m0 = blockIdx.x * 64;
    const int tid = threadIdx.x;
    const int lane = tid & 63, wid = tid >> 6;
    const int l15 = lane & 15, l4 = lane >> 4;

    const u16* Qg = QKVb + (long)(zb * 256) * 3072 + zn * 256;
    const u16* Kg = Qg + 1024;   // holds K/32

    auto stageA64 = [&](const u16* g, long ld) {
#pragma unroll
        for (int p = 0; p < 2; ++p) {
            const int e = p * 2048 + tid * 8;
            const int r = e >> 6, c = e & 63;
            const int sc = c ^ SWZ(r);
            gld16(&As[e], g + (long)r * ld + sc);
        }
    };
    auto stageB256 = [&](const u16* g, long ld) {
#pragma unroll
        for (int p = 0; p < 8; ++p) {
            const int e = p * 2048 + tid * 8;
            const int r = e >> 6, c = e & 63;
            const int sc = c ^ SWZ(r);
            gld16(&Bs[e], g + (long)r * ld + sc);
        }
    };
    auto fragA = [&](int i, int kk) -> bf16x8 {
        const int row = i * 16 + l15, col = kk * 32 + l4 * 8;
        return *(const bf16x8*)&As[row * 64 + (col ^ SWZ(row))];
    };
    auto fragB = [&](int j, int kk) -> bf16x8 {
        const int row = wid * 64 + j * 16 + l15, col = kk * 32 + l4 * 8;
        return *(const bf16x8*)&Bs[row * 64 + (col ^ SWZ(row))];
    };
    auto fragP = [&](int kc, int i, int kk) -> bf16x8 {
        const int row = i * 16 + l15, col = kk * 32 + l4 * 8;
        return *(const bf16x8*)&Pl[kc * 4096 + row * 64 + (col ^ SWZ(row))];
    };

    f32x4 acc1[4][4] = {};

    for (int kc = 0; kc < 8; ++kc) {
        __syncthreads();
        if (kc < 4) {
            stageA64(Qg + (long)m0 * 3072 + kc * 64, 3072);
            stageB256(Kg + kc * 64, 3072);
        } else {
            stageA64(erT + (long)m0 * 256 + (kc - 4) * 64, 256);
            stageB256(Qg + (kc - 4) * 64, 3072);
        }
        __syncthreads();
#pragma unroll
        for (int i = 0; i < 4; ++i) {
            const bf16x8 a0 = fragA(i, 0), a1 = fragA(i, 1);
#pragma unroll
            for (int j = 0; j < 4; ++j) {
                acc1[i][j] = __builtin_amdgcn_mfma_f32_16x16x32_bf16(a0, fragB(j, 0), acc1[i][j], 0, 0, 0);
                acc1[i][j] = __builtin_amdgcn_mfma_f32_16x16x32_bf16(a1, fragB(j, 1), acc1[i][j], 0, 0, 0);
            }
        }
    }

#pragma unroll
    for (int i = 0; i < 4; ++i)
#pragma unroll
        for (int q = 0; q < 4; ++q) {
            const int mg = m0 + i * 16 + l4 * 4 + q;
            const float dw = dwp[zn * 256 + mg];
#pragma unroll
            for (int j = 0; j < 4; ++j) {
                const int ng = wid * 64 + j * 16 + l15;
                acc1[i][j][q] += fabsf((float)(mg - ng)) * 0.5f * dw;
            }
        }

    float rmax[4][4], rsum[4][4];
#pragma unroll
    for (int i = 0; i < 4; ++i)
#pragma unroll
        for (int q = 0; q < 4; ++q) {
            float mv = fmaxf(fmaxf(acc1[i][0][q], acc1[i][1][q]),
                             fmaxf(acc1[i][2][q], acc1[i][3][q]));
#pragma unroll
            for (int off = 1; off <= 8; off <<= 1) mv = fmaxf(mv, __shfl_xor(mv, off, 64));
            rmax[i][q] = mv;
        }
    if (l15 == 0) {
#pragma unroll
        for (int i = 0; i < 4; ++i)
#pragma unroll
            for (int q = 0; q < 4; ++q)
                redM[wid][i * 16 + l4 * 4 + q] = rmax[i][q];
    }
    __syncthreads();
#pragma unroll
    for (int i = 0; i < 4; ++i)
#pragma unroll
        for (int q = 0; q < 4; ++q) {
            const int ml = i * 16 + l4 * 4 + q;
            rmax[i][q] = fmaxf(fmaxf(redM[0][ml], redM[1][ml]), fmaxf(redM[2][ml], redM[3][ml]));
        }
#pragma unroll
    for (int i = 0; i < 4; ++i)
#pragma unroll
        for (int q = 0; q < 4; ++q) {
            float sv = 0.f;
#pragma unroll
            for (int j = 0; j < 4; ++j) {
                const float e = __expf(acc1[i][j][q] - rmax[i][q]);
                acc1[i][j][q] = e;
                sv += e;
            }
#pragma unroll
            for (int off = 1; off <= 8; off <<= 1) sv += __shfl_xor(sv, off, 64);
            rsum[i][q] = sv;
        }
    if (l15 == 0) {
#pragma unroll
        for (int i = 0; i < 4; ++i)
#pragma unroll
            for (int q = 0; q < 4; ++q)
                redS[wid][i * 16 + l4 * 4 + q] = rsum[i][q];
    }
    __syncthreads();
#pragma unroll
    for (int i = 0; i < 4; ++i)
#pragma unroll
        for (int q = 0; q < 4; ++q) {
            const int ml = i * 16 + l4 * 4 + q;
            rsum[i][q] = redS[0][ml] + redS[1][ml] + redS[2][ml] + redS[3][ml];
        }
#pragma unroll
    for (int i = 0; i < 4; ++i)
#pragma unroll
        for (int q = 0; q < 4; ++q) {
            const float rinv = 1.f / rsum[i][q];
            const int ml = i * 16 + l4 * 4 + q;
#pragma unroll
            for (int j = 0; j < 4; ++j) {
                const int nc = j * 16 + l15;
                Pl[wid * 4096 + ml * 64 + (nc ^ SWZ(ml))] = f2bf(acc1[i][j][q] * rinv);
            }
        }
    __syncthreads();

    f32x4 accO[4][4] = {};
    for (int kc = 0; kc < 4; ++kc) {
        __syncthreads();
        stageB256(Vt + (long)(z * 256) * 256 + kc * 64, 256);
        __syncthreads();
#pragma unroll
        for (int i = 0; i < 4; ++i) {
            const bf16x8 a0 = fragP(kc, i, 0), a1 = fragP(kc, i, 1);
#pragma unroll
            for (int j = 0; j < 4; ++j) {
                accO[i][j] = __builtin_amdgcn_mfma_f32_16x16x32_bf16(a0, fragB(j, 0), accO[i][j], 0, 0, 0);
                accO[i][j] = __builtin_amdgcn_mfma_f32_16x16x32_bf16(a1, fragB(j, 1), accO[i][j], 0, 0, 0);
            }
        }
    }

#pragma unroll
    for (int i = 0; i < 4; ++i)
#pragma unroll
        for (int j = 0; j < 4; ++j) {
            const int d = wid * 64 + j * 16 + l15;
#pragma unroll
            for (int q = 0; q < 4; ++q) {
                const int mg = m0 + i * 16 + l4 * 4 + q;
                Oc[(long)(zb * 256 + mg) * 1024 + zn * 256 + d] = f2bf(accO[i][j][q]);
            }
        }
}

// ---------------- GLU gate + residual + LN (bf16 chain, 2 bf16 partials) ----------------
__global__ __launch_bounds__(256)
void glu_ln_k(const u16* __restrict__ xs0, const u16* __restrict__ g2,
              const float* __restrict__ gam, const float* __restrict__ bet,
              u16* __restrict__ outb)
{
    const int t = blockIdx.x, tid = threadIdx.x;
    const int f0 = tid * 4;
    const long PS = 8388608;
    const float4 xv = bf4f(*(const ushort4*)&xs0[(long)t * 1024 + f0]);
    const float4 a0 = bf4f(*(const ushort4*)&g2[(long)t * 2048 + f0]);
    const float4 g0 = bf4f(*(const ushort4*)&g2[(long)t * 2048 + 1024 + f0]);
    const float4 a1 = bf4f(*(const ushort4*)&g2[PS + (long)t * 2048 + f0]);
    const float4 g1 = bf4f(*(const ushort4*)&g2[PS + (long)t * 2048 + 1024 + f0]);
    const float ax = a0.x + a1.x, ay = a0.y + a1.y, az = a0.z + a1.z, aw = a0.w + a1.w;
    const float gx = g0.x + g1.x, gy = g0.y + g1.y, gz = g0.z + g1.z, gw = g0.w + g1.w;
    float vals[4];
    vals[0] = xv.x + ax / (1.f + expf(-gx));
    vals[1] = xv.y + ay / (1.f + expf(-gy));
    vals[2] = xv.z + az / (1.f + expf(-gz));
    vals[3] = xv.w + aw / (1.f + expf(-gw));
    float s1 = vals[0] + vals[1] + vals[2] + vals[3];
    float s2 = vals[0]*vals[0] + vals[1]*vals[1] + vals[2]*vals[2] + vals[3]*vals[3];
    block_red2(s1, s2, tid);
    const float mean = s1 * (1.f / 1024.f);
    const float var  = s2 * (1.f / 1024.f) - mean * mean;
    const float rstd = rsqrtf(var + EPSF);
    const float4 gm = *(const float4*)&gam[f0];
    const float4 bt = *(const float4*)&bet[f0];
    *(ushort4*)&outb[(long)t * 1024 + f0] = f4bf(
        (vals[0] - mean) * rstd * gm.x + bt.x,
        (vals[1] - mean) * rstd * gm.y + bt.y,
        (vals[2] - mean) * rstd * gm.z + bt.z,
        (vals[3] - mean) * rstd * gm.w + bt.w);
}

// ---------------- residual add + LN width 1024 (bf16 chain, P bf16 partials, opt bias) ----------------
template<int P, int BIAS>
__global__ __launch_bounds__(256)
void add_ln1024_k(const u16* __restrict__ A, const u16* __restrict__ Bp,
                  const float* __restrict__ bias,
                  const float* __restrict__ gam, const float* __restrict__ bet,
                  u16* __restrict__ outb)
{
    const int t = blockIdx.x, tid = threadIdx.x;
    const int f0 = tid * 4;
    const long PS = 4194304;
    const float4 a = bf4f(*(const ushort4*)&A[(long)t * 1024 + f0]);
    float4 b = bf4f(*(const ushort4*)&Bp[(long)t * 1024 + f0]);
#pragma unroll
    for (int p = 1; p < P; ++p) {
        const float4 bp = bf4f(*(const ushort4*)&Bp[p * PS + (long)t * 1024 + f0]);
        b.x += bp.x; b.y += bp.y; b.z += bp.z; b.w += bp.w;
    }
    if (BIAS) {
        const float4 bb = *(const float4*)&bias[f0];
        b.x += bb.x; b.y += bb.y; b.z += bb.z; b.w += bb.w;
    }
    float vals[4] = {a.x + b.x, a.y + b.y, a.z + b.z, a.w + b.w};
    float s1 = vals[0] + vals[1] + vals[2] + vals[3];
    float s2 = vals[0]*vals[0] + vals[1]*vals[1] + vals[2]*vals[2] + vals[3]*vals[3];
    block_red2(s1, s2, tid);
    const float mean = s1 * (1.f / 1024.f);
    const float var  = s2 * (1.f / 1024.f) - mean * mean;
    const float rstd = rsqrtf(var + EPSF);
    const float4 gm = *(const float4*)&gam[f0];
    const float4 bt = *(const float4*)&bet[f0];
    *(ushort4*)&outb[(long)t * 1024 + f0] = f4bf(
        (vals[0] - mean) * rstd * gm.x + bt.x,
        (vals[1] - mean) * rstd * gm.y + bt.y,
        (vals[2] - mean) * rstd * gm.z + bt.z,
        (vals[3] - mean) * rstd * gm.w + bt.w);
}

// ---------------- n2: LN(c1L(bf16) + pad(relu(sum of 3 bf16 conv taps))) width 4096 ----------------
__global__ __launch_bounds__(256)
void add_ln4096_k(const u16* __restrict__ A, const u16* __restrict__ Bp,
                  const float* __restrict__ gam, const float* __restrict__ bet,
                  u16* __restrict__ outb)
{
    const int t = blockIdx.x, tid = threadIdx.x;
    const long PS = 4194304;
    const int f0 = tid * 16;
    float vals[16];
    const bf16x8 a0 = *(const bf16x8*)&A[(long)t * 4096 + f0];
    const bf16x8 a1 = *(const bf16x8*)&A[(long)t * 4096 + f0 + 8];
#pragma unroll
    for (int e = 0; e < 8; ++e) { vals[e] = bf2f((u16)a0[e]); vals[8 + e] = bf2f((u16)a1[e]); }
    if (tid < 64) {
#pragma unroll
        for (int c = 0; c < 4; ++c) {
            const int fc = f0 + c * 4;
            const float4 b0 = bf4f(*(const ushort4*)&Bp[(long)t * 1024 + fc]);
            const float4 b1 = bf4f(*(const ushort4*)&Bp[PS + (long)t * 1024 + fc]);
            const float4 b2 = bf4f(*(const ushort4*)&Bp[2 * PS + (long)t * 1024 + fc]);
            vals[c*4+0] += fmaxf(b0.x + b1.x + b2.x, 0.f);
            vals[c*4+1] += fmaxf(b0.y + b1.y + b2.y, 0.f);
            vals[c*4+2] += fmaxf(b0.z + b1.z + b2.z, 0.f);
            vals[c*4+3] += fmaxf(b0.w + b1.w + b2.w, 0.f);
        }
    }
    float s1 = 0.f, s2 = 0.f;
#pragma unroll
    for (int e = 0; e < 16; ++e) { s1 += vals[e]; s2 += vals[e] * vals[e]; }
    block_red2(s1, s2, tid);
    const float mean = s1 * (1.f / 4096.f);
    const float var  = s2 * (1.f / 4096.f) - mean * mean;
    const float rstd = rsqrtf(var + EPSF);
#pragma unroll
    for (int c = 0; c < 4; ++c) {
        const int fc = f0 + c * 4;
        const float4 gm = *(const float4*)&gam[fc];
        const float4 bt = *(const float4*)&bet[fc];
        *(ushort4*)&outb[(long)t * 4096 + fc] = f4bf(
            (vals[c*4+0] - mean) * rstd * gm.x + bt.x,
            (vals[c*4+1] - mean) * rstd * gm.y + bt.y,
            (vals[c*4+2] - mean) * rstd * gm.z + bt.z,
            (vals[c*4+3] - mean) * rstd * gm.w + bt.w);
    }
}

// ---------------- depthwise conv width-9, 8 channels/thread ----------------
__global__ __launch_bounds__(256)
void dwconv8_k(const u16* __restrict__ h, const float* __restrict__ wT,
               u16* __restrict__ out)
{
    const long idx = (long)blockIdx.x * 256 + threadIdx.x;
    const int cg = (int)(idx & 511);
    const int t  = (int)(idx >> 9);
    const int w  = t & 255;
    const int c0 = cg * 8;
    float acc[8] = {};
#pragma unroll
    for (int k = 0; k < 9; ++k) {
        const int wp = w + k - 4;
        if ((unsigned)wp < 256u) {
            const bf16x8 hv = *(const bf16x8*)&h[(long)(t + k - 4) * 4096 + c0];
            const float4 w0 = *(const float4*)&wT[k * 4096 + c0];
            const float4 w1 = *(const float4*)&wT[k * 4096 + c0 + 4];
            acc[0] += bf2f((u16)hv[0]) * w0.x;
            acc[1] += bf2f((u16)hv[1]) * w0.y;
            acc[2] += bf2f((u16)hv[2]) * w0.z;
            acc[3] += bf2f((u16)hv[3]) * w0.w;
            acc[4] += bf2f((u16)hv[4]) * w1.x;
            acc[5] += bf2f((u16)hv[5]) * w1.y;
            acc[6] += bf2f((u16)hv[6]) * w1.z;
            acc[7] += bf2f((u16)hv[7]) * w1.w;
        }
    }
    bf16x8 res;
#pragma unroll
    for (int j = 0; j < 8; ++j) res[j] = (short)f2bf(acc[j]);
    *(bf16x8*)&out[(long)t * 4096 + c0] = res;
}

// ---------------- final transpose: bf16 (tokens,1024) -> f32 (B,1,1024,256) ----------------
__global__ __launch_bounds__(256)
void transpose_out_k(const u16* __restrict__ xs, float* __restrict__ out)
{
    __shared__ u16 tile[32][34];
    const int b = blockIdx.z, f0 = blockIdx.y * 32, w0 = blockIdx.x * 32;
    const int tid = threadIdx.x, c = tid & 31, r = tid >> 5;
#pragma unroll
    for (int it = 0; it < 4; ++it) {
        const int w = w0 + r + it * 8;
        tile[r + it * 8][c] = xs[((long)b * 256 + w) * 1024 + f0 + c];
    }
    __syncthreads();
#pragma unroll
    for (int it = 0; it < 4; ++it) {
        const int fl = r + it * 8;
        out[((long)b * 1024 + f0 + fl) * 256 + w0 + c] = bf2f(tile[c][fl]);
    }
}

// =======================================================================
extern "C" void kernel_launch(void* const* d_in, const int* in_sizes, int n_in,
                              void* d_out, int out_size, void* d_ws, size_t ws_size,
                              hipStream_t stream)
{
    const float* x      = (const float*)d_in[0];
    const float* bott_w = (const float*)d_in[1];
    const float* bn_g   = (const float*)d_in[2];
    const float* bn_b   = (const float*)d_in[3];
    const float* bn_m   = (const float*)d_in[4];
    const float* bn_v   = (const float*)d_in[5];
    const float* glu_w  = (const float*)d_in[6];
    const float* n1g    = (const float*)d_in[7];
    const float* n1b    = (const float*)d_in[8];
    const float* c1L_w  = (const float*)d_in[9];
    const float* c1R_w  = (const float*)d_in[10];
    const float* n2g    = (const float*)d_in[11];
    const float* n2b    = (const float*)d_in[12];
    const float* c2dw_w = (const float*)d_in[13];
    const float* c2pw_w = (const float*)d_in[14];
    const float* n3g    = (const float*)d_in[15];
    const float* n3b    = (const float*)d_in[16];
    const float* qw     = (const float*)d_in[17];
    const float* qb     = (const float*)d_in[18];
    const float* kw     = (const float*)d_in[19];
    const float* kb     = (const float*)d_in[20];
    const float* vw     = (const float*)d_in[21];
    const float* vb     = (const float*)d_in[22];
    const float* ow     = (const float*)d_in[23];
    const float* ob     = (const float*)d_in[24];
    const float* er     = (const float*)d_in[25];
    const float* dist_w = (const float*)d_in[26];
    const float* n4g    = (const float*)d_in[27];
    const float* n4b    = (const float*)d_in[28];
    const float* c3_w   = (const float*)d_in[29];
    const float* c4_w   = (const float*)d_in[30];
    const float* n5g    = (const float*)d_in[31];
    const float* n5b    = (const float*)d_in[32];
    float* out = (float*)d_out;

    // ---- workspace layout (MiB offsets, bf16 residual chain) ----
    char* Wb_ = (char*)d_ws;
    auto Bf = [&](size_t mib) { return (u16*)(Wb_ + (mib << 20)); };
    u16* XA   = Bf(0);    // xs0 (1-3), xs2 (9-13), xs4 (16-17)
    u16* XB   = Bf(8);    // xs1 (3-9), xs3 (13-16)
    u16* H0b  = Bf(32);   // c1L out (4-6) / c3 out (14-15)
    u16* Hglu = Bf(64);   // GLU 2 bf16 partials (2-3)
    u16* C3p  = Bf(64);   // conv3 3 bf16 partials (5-6)
    u16* P4   = Bf(64);   // c2pw/O-proj/c4 4 bf16 partials
    u16* H1b  = Bf(128);  // n2 out (6-7)
    u16* Hdw  = Bf(160);  // dwconv out (7-8)
    u16* QKVb = Bf(192);  // QKV out 4096x3072 (10-11; V cols dead, written to Vt)
    u16* Vt   = Bf(216);  // V transposed (10-11)
    u16* S1b  = Bf(264);  // attn concat out (11-12)
    u16* wGLU = Bf(296); u16* wC1L = Bf(300); u16* wC1R = Bf(308);
    u16* wC2P = Bf(314); u16* wQKV = Bf(322); u16* wO   = Bf(328);
    u16* wC3  = Bf(330); u16* wC4  = Bf(338);
    u16* erT  = Bf(346);
    u16* zp   = (u16*)(Wb_ + (346u << 20) + 131072);
    float* wdwT = (float*)(Wb_ + (346u << 20) + 131072 + 16384);
    float* bQKV = (float*)(Wb_ + (346u << 20) + 131072 + 16384 + 147456);

    const dim3 blk(256);
    const dim3 blk8(512);
    const long PS1 = 4194304;
    const size_t SH8 = 131072;

    // 0. merged setup (one launch); kw/kb pre-scaled by 1/32
    SetupArgs sa;
    sa.ws[0] = glu_w;  sa.wd[0] = wGLU;            sa.wn[0] = 524288;
    sa.ws[1] = c1L_w;  sa.wd[1] = wC1L;            sa.wn[1] = 1048576;
    sa.ws[2] = c2pw_w; sa.wd[2] = wC2P;            sa.wn[2] = 1048576;
    sa.ws[3] = c3_w;   sa.wd[3] = wC3;             sa.wn[3] = 1048576;
    sa.ws[4] = c4_w;   sa.wd[4] = wC4;             sa.wn[4] = 1048576;
    sa.ws[5] = qw;     sa.wd[5] = wQKV;            sa.wn[5] = 262144;
    sa.ws[6] = kw;     sa.wd[6] = wQKV + 1048576;  sa.wn[6] = 262144;
    sa.ws[7] = vw;     sa.wd[7] = wQKV + 2097152;  sa.wn[7] = 262144;
    sa.ws[8] = ow;     sa.wd[8] = wO;              sa.wn[8] = 262144;
    sa.c1r = c1R_w; sa.c1rd = wC1R;
    sa.er  = er;    sa.erd  = erT;
    sa.dw  = c2dw_w; sa.dwd = wdwT;
    sa.qb = qb; sa.kb = kb; sa.vb = vb; sa.bcat = bQKV;
    sa.zp = zp;
    {
        int bc[14] = {2048, 4096, 4096, 4096, 4096, 1024, 1024, 1024, 1024,
                      12288, 256, 144, 12, 32};
        int acc = 0;
        for (int s = 0; s < 14; ++s) { sa.off[s] = acc; acc += bc[s]; }
        sa.off[14] = acc;
        setup_k<<<dim3(acc), blk, 0, stream>>>(sa);
    }

    // 1. bottleneck + BN + ReLU + transpose -> XA (xs0, bf16)
    bottleneck_k<<<dim3(8, 32, 16), blk, 0, stream>>>(x, bott_w, bn_g, bn_b, bn_m, bn_v, XA);

    // 2. GLU matmul, split-K=2 -> Hglu bf16 partials
    gemm8_k<0,0,0,2,0><<<dim3(8, 16, 2), blk8, SH8, stream>>>(XA, wGLU, nullptr, Hglu,
        2048, 512, 1024, 1024, (long)4096 * 2048, nullptr);

    // 3. n1: LN(xs0 + a*sigmoid(g)) -> XB (xs1)
    glu_ln_k<<<dim3(4096), blk, 0, stream>>>(XA, Hglu, n1g, n1b, XB);

    // 4+5. merged c1L (relu -> H0b) + conv1R taps (-> C3p partials), one launch
    ffconv8_k<<<dim3(28, 16), blk8, SH8, stream>>>(XB, wC1L, wC1R, zp, H0b, C3p);

    // 6. n2: LN(H0b + pad(relu(sum taps))) -> H1b bf16
    add_ln4096_k<<<dim3(4096), blk, 0, stream>>>(H0b, C3p, n2g, n2b, H1b);

    // 7. depthwise conv9 (vectorized x8): H1b -> Hdw
    dwconv8_k<<<dim3(8192), blk, 0, stream>>>(H1b, wdwT, Hdw);

    // 8. c2pw, split-K=4 -> P4 bf16 partials
    gemm8_k<0,0,0,4,0><<<dim3(4, 16, 4), blk8, SH8, stream>>>(Hdw, wC2P, nullptr, P4,
        1024, 1024, 4096, 4096, PS1, nullptr);

    // 9. n3: LN(xs1 + sum P4) -> XA (xs2)
    add_ln1024_k<4,0><<<dim3(4096), blk, 0, stream>>>(XB, P4, nullptr, n3g, n3b, XA);

    // 10. fused QKV projection; V-tiles written transposed to Vt in-epilogue
    gemm8_k<0,1,1,1,1><<<dim3(12, 16, 1), blk8, SH8, stream>>>(XA, wQKV, bQKV, QKVb,
        3072, 1024, 1024, 1024, 0, Vt);

    // 11. fused attention: K=512 concat scores + softmax + PV -> S1b
    attn_fused_k<<<dim3(4, 64), blk, 0, stream>>>(QKVb, erT, Vt, dist_w, S1b);

    // 12. output projection, split-K=4 -> P4 bf16 partials (bias added in n4)
    gemm8_k<0,0,0,4,0><<<dim3(4, 16, 4), blk8, SH8, stream>>>(S1b, wO, nullptr, P4,
        1024, 256, 1024, 1024, PS1, nullptr);

    // 13. n4: LN(xs2 + sum P4 + ob) -> XB (xs3)
    add_ln1024_k<4,1><<<dim3(4096), blk, 0, stream>>>(XA, P4, ob, n4g, n4b, XB);

    // 14. c3: relu -> H0b bf16
    gemm8_k<1,1,0,1,0><<<dim3(16, 16, 1), blk8, SH8, stream>>>(XB, wC3, nullptr, H0b,
        4096, 1024, 1024, 1024, 0, nullptr);

    // 15. c4, split-K=4 -> P4 bf16 partials
    gemm8_k<0,0,0,4,0><<<dim3(4, 16, 4), blk8, SH8, stream>>>(H0b, wC4, nullptr, P4,
        1024, 1024, 4096, 4096, PS1, nullptr);

    // 16. n5: LN(xs3 + sum P4) -> XA (xs4, bf16)
    add_ln1024_k<4,0><<<dim3(4096), blk, 0, stream>>>(XB, P4, nullptr, n5g, n5b, XA);

    // 17. transpose to (B, 1, 1024, 256) f32
    transpose_out_k<<<dim3(8, 32, 16), blk, 0, stream>>>(XA, out);

    (void)in_sizes; (void)n_in; (void)out_size; (void)ws_size;
}